// Round 3
// baseline (346.615 us; speedup 1.0000x reference)
//
#include <hip/hip_runtime.h>

typedef float floatx4 __attribute__((ext_vector_type(4)));
typedef short short8 __attribute__((ext_vector_type(8)));

#define HIDDEN 2048
#define NH 16
#define NKV 4
#define HD 128
#define NB 2
#define SEQ 2048
#define MT (NB * SEQ)  // 4096
#define NQKV 3072      // fused projection width: 2048 Q + 512 K + 512 V

#define MFMA16(a, b, c) __builtin_amdgcn_mfma_f32_16x16x32_bf16(a, b, c, 0, 0, 0)
#define S_BAR() __builtin_amdgcn_s_barrier()
// lgkmcnt(0) before MFMA needs the sched_barrier fence (rule #18)
#define WAIT_LGKM0() do { asm volatile("s_waitcnt lgkmcnt(0)" ::: "memory"); \
                          __builtin_amdgcn_sched_barrier(0); } while (0)
// counted vmcnt: NO sched_barrier (m141: order-pinning regresses)
#define WAIT_VM(N) asm volatile("s_waitcnt vmcnt(" #N ")" ::: "memory")
#define LGKM_HINT8() asm volatile("s_waitcnt lgkmcnt(8)" ::: "memory")

__device__ __forceinline__ unsigned short f2bf(float x) {
  union { float f; unsigned u; } v; v.f = x;
  unsigned r = v.u + 0x7FFFu + ((v.u >> 16) & 1u);  // RNE
  return (unsigned short)(r >> 16);
}

__device__ __forceinline__ unsigned int cvt_pk_bf16(float lo, float hi) {
  unsigned int r;
  asm("v_cvt_pk_bf16_f32 %0, %1, %2" : "=v"(r) : "v"(lo), "v"(hi));
  return r;
}

// ---------------- contiguous fp32 -> bf16 cast ----------------
__global__ void cast_bf16_kernel(const float* __restrict__ in,
                                 unsigned short* __restrict__ out, int n4) {
  int i = blockIdx.x * 256 + threadIdx.x;
  if (i >= n4) return;
  float4 v = ((const float4*)in)[i];
  ushort4 o;
  o.x = f2bf(v.x); o.y = f2bf(v.y); o.z = f2bf(v.z); o.w = f2bf(v.w);
  ((ushort4*)out)[i] = o;
}

// ------- fused weight transpose + cast -------
__global__ void wtrans_kernel(const float* __restrict__ Wq,
                              const float* __restrict__ Wk,
                              const float* __restrict__ Wv,
                              const float* __restrict__ Wo,
                              unsigned short* __restrict__ wqkvt,
                              unsigned short* __restrict__ wot) {
  __shared__ float tile[32][33];
  int z = blockIdx.z;
  int nt = blockIdx.x * 32;
  int k0 = blockIdx.y * 32;
  const float* src;
  unsigned short* dst;
  int Nd, scol0, drow0;
  if (z == 0) {
    src = Wq; Nd = 2048; scol0 = nt; drow0 = nt; dst = wqkvt;
  } else if (z == 1) {
    src = Wo; Nd = 2048; scol0 = nt; drow0 = nt; dst = wot;
  } else {
    if (nt >= 1024) return;
    Nd = 512; dst = wqkvt; drow0 = 2048 + nt;
    if (nt < 512) { src = Wk; scol0 = nt; }
    else          { src = Wv; scol0 = nt - 512; }
  }
  int tx = threadIdx.x, ty = threadIdx.y;
  for (int i = 0; i < 32; i += 8)
    tile[ty + i][tx] = src[(size_t)(k0 + ty + i) * Nd + scol0 + tx];
  __syncthreads();
  for (int i = 0; i < 32; i += 8)
    dst[(size_t)(drow0 + ty + i) * HIDDEN + k0 + tx] = f2bf(tile[tx][ty + i]);
}

// =====================================================================
// Repaired 8-phase 256-tile GEMM (template-faithful):
//  - TWO barriers per phase: [ds_reads; stage; BAR; lgkm0; prio1 MFMA prio0; BAR]
//  - deep prefetch: P2 stages B0,B1(Y+2) (B slot free after P1's closing BAR);
//    P3 stages A0,A1(Y+2) (A slot free after P2's closing BAR).
//    A-depth 5 phases / B-depth 6 phases; WAIT_VM(loads-per-tile) at tile end
//    guarantees tile Y+1 fully landed; vmcnt(0) only in the tail.
//  - LDS swizzle: 16B chunk c of row r at c ^ (r&7); inverse applied to the
//    GLOBAL source of global_load_lds (linear LDS dest, rule #21).
//  - bijective XCD remap (nwg % 8 == 0 for both grids).
// =====================================================================

// ------- QKV GEMM (BM=256, BN=256: N-tile = 2 heads) + fused epilogue ----
__global__ __launch_bounds__(512, 1)
void gemm_qkv_kernel(const unsigned short* __restrict__ A,    // hb [MT][2048]
                     const unsigned short* __restrict__ Bt,   // wqkvt [3072][2048]
                     const float* __restrict__ qw,
                     const float* __restrict__ kw,
                     const float* __restrict__ cosb,
                     const float* __restrict__ sinb,
                     unsigned short* __restrict__ Qb,   // [NB][NH][SEQ][HD]
                     unsigned short* __restrict__ Kbb,  // [NB][NKV][SEQ][HD]
                     unsigned short* __restrict__ Vt) { // [NB][NKV][HD][SEQ]
  extern __shared__ __align__(16) char smem[];  // 128 KiB: A dbuf 64K | B dbuf 64K
  const int tid = threadIdx.x;
  const int wave = tid >> 6, lane = tid & 63;
  const int quad = lane >> 4, l16 = lane & 15;
  // bijective XCD remap: 16x12=192 blocks, 192%8==0
  const int nwg = gridDim.x * gridDim.y;
  const int orig = blockIdx.x + gridDim.x * blockIdx.y;
  const int lin = (orig & 7) * (nwg >> 3) + (orig >> 3);
  const int bx = lin % gridDim.x, by = lin / gridDim.x;
  const int m0 = bx * 256, n0 = by * 256;
  const int wm = (wave >> 2) * 128, wn = (wave & 3) * 64;

  const int sgrow = wave * 8 + (lane >> 3);                    // staging row
  const int swzcol = (((lane & 7) ^ ((lane >> 3) & 7)) << 4);  // inverse-swizzled col
  const int laneA0 = l16 * 128 + ((quad ^ (l16 & 7)) << 4);    // swizzled ds_read col
  const int laneA1 = laneA0 ^ 64;

  auto stageA = [&](int T, int h) {
    const char* g = (const char*)A + (((size_t)(m0 + h * 128)) * HIDDEN + T * 64) * 2;
    char* l = smem + (size_t)(((T & 1) * 2 + h) * 16384) + wave * 1024;
#pragma unroll
    for (int ii = 0; ii < 2; ++ii) {
      const char* src = g + (size_t)(ii * 64 + sgrow) * (HIDDEN * 2) + swzcol;
      __builtin_amdgcn_global_load_lds(
          (const __attribute__((address_space(1))) unsigned int*)src,
          (__attribute__((address_space(3))) unsigned int*)(l + ii * 8192), 16, 0, 0);
    }
  };
  auto stageB = [&](int T, int h) {
    const char* g = (const char*)Bt + (((size_t)(n0 + h * 128)) * HIDDEN + T * 64) * 2;
    char* l = smem + 65536 + (size_t)(((T & 1) * 2 + h) * 16384) + wave * 1024;
#pragma unroll
    for (int ii = 0; ii < 2; ++ii) {
      const char* src = g + (size_t)(ii * 64 + sgrow) * (HIDDEN * 2) + swzcol;
      __builtin_amdgcn_global_load_lds(
          (const __attribute__((address_space(1))) unsigned int*)src,
          (__attribute__((address_space(3))) unsigned int*)(l + ii * 8192), 16, 0, 0);
    }
  };

  floatx4 acc[8][4] = {};
  short8 a[4][2], bA[2][2], bB[2][2];
  const int NT = HIDDEN / 64;  // 32

  // prologue: tiles 0 and 1 fully staged; wait tile0 (tile1's 8 may float)
  stageA(0, 0); stageA(0, 1); stageB(0, 0); stageB(0, 1);
  stageA(1, 0); stageA(1, 1); stageB(1, 0); stageB(1, 1);
  WAIT_VM(8);
  S_BAR();

#pragma unroll 1
  for (int Y = 0; Y < NT; ++Y) {
    const int cb = Y & 1;
    const char* Ah = smem + (size_t)((cb * 2 + (wave >> 2)) * 16384);
    const char* Bh = smem + 65536 + (size_t)((cb * 2 + ((wave & 3) >> 1)) * 16384) +
                     (wn & 64) * 128;
    // ---- P0: ds a[M0](8) + bA(4); mfma (M0,N0) ----
#pragma unroll
    for (int fi = 0; fi < 4; ++fi) {
      a[fi][0] = *(const short8*)(Ah + fi * 2048 + laneA0);
      a[fi][1] = *(const short8*)(Ah + fi * 2048 + laneA1);
    }
#pragma unroll
    for (int fj = 0; fj < 2; ++fj) {
      bA[fj][0] = *(const short8*)(Bh + fj * 2048 + laneA0);
      bA[fj][1] = *(const short8*)(Bh + fj * 2048 + laneA1);
    }
    LGKM_HINT8();
    S_BAR();
    WAIT_LGKM0();
    __builtin_amdgcn_s_setprio(1);
#pragma unroll
    for (int fi = 0; fi < 4; ++fi)
#pragma unroll
      for (int fj = 0; fj < 2; ++fj) {
        acc[fi][fj] = MFMA16(a[fi][0], bA[fj][0], acc[fi][fj]);
        acc[fi][fj] = MFMA16(a[fi][1], bA[fj][1], acc[fi][fj]);
      }
    __builtin_amdgcn_s_setprio(0);
    S_BAR();
    // ---- P1: ds bB(4); mfma (M0,N1) ----
#pragma unroll
    for (int fj = 0; fj < 2; ++fj) {
      bB[fj][0] = *(const short8*)(Bh + 4096 + fj * 2048 + laneA0);
      bB[fj][1] = *(const short8*)(Bh + 4096 + fj * 2048 + laneA1);
    }
    S_BAR();
    WAIT_LGKM0();
    __builtin_amdgcn_s_setprio(1);
#pragma unroll
    for (int fi = 0; fi < 4; ++fi)
#pragma unroll
      for (int fj = 0; fj < 2; ++fj) {
        acc[fi][2 + fj] = MFMA16(a[fi][0], bB[fj][0], acc[fi][2 + fj]);
        acc[fi][2 + fj] = MFMA16(a[fi][1], bB[fj][1], acc[fi][2 + fj]);
      }
    __builtin_amdgcn_s_setprio(0);
    S_BAR();
    // ---- P2: ds a[M1](8); stage B0,B1(Y+2) (B slot free after P1); mfma (M1,N1) ----
#pragma unroll
    for (int fi = 0; fi < 4; ++fi) {
      a[fi][0] = *(const short8*)(Ah + 8192 + fi * 2048 + laneA0);
      a[fi][1] = *(const short8*)(Ah + 8192 + fi * 2048 + laneA1);
    }
    if (Y + 2 < NT) { stageB(Y + 2, 0); stageB(Y + 2, 1); }
    S_BAR();
    WAIT_LGKM0();
    __builtin_amdgcn_s_setprio(1);
#pragma unroll
    for (int fi = 0; fi < 4; ++fi)
#pragma unroll
      for (int fj = 0; fj < 2; ++fj) {
        acc[4 + fi][2 + fj] = MFMA16(a[fi][0], bB[fj][0], acc[4 + fi][2 + fj]);
        acc[4 + fi][2 + fj] = MFMA16(a[fi][1], bB[fj][1], acc[4 + fi][2 + fj]);
      }
    __builtin_amdgcn_s_setprio(0);
    S_BAR();
    // ---- P3: stage A0,A1(Y+2) (A slot free after P2); mfma (M1,N0) ----
    if (Y + 2 < NT) { stageA(Y + 2, 0); stageA(Y + 2, 1); }
    S_BAR();
    __builtin_amdgcn_s_setprio(1);
#pragma unroll
    for (int fi = 0; fi < 4; ++fi)
#pragma unroll
      for (int fj = 0; fj < 2; ++fj) {
        acc[4 + fi][fj] = MFMA16(a[fi][0], bA[fj][0], acc[4 + fi][fj]);
        acc[4 + fi][fj] = MFMA16(a[fi][1], bA[fj][1], acc[4 + fi][fj]);
      }
    __builtin_amdgcn_s_setprio(0);
    if (Y + 2 < NT) { WAIT_VM(8); } else { WAIT_VM(0); }
    S_BAR();
  }

  // ================= fused epilogue =================
  const int tileN = by;
  const int head2 = tileN * 2 + ((wave & 3) >> 1);  // this wave's head

  if (tileN >= 10) {
    // ---- V path: cast + write transposed Vt[b][kv][d][s] (s packed x4) ----
    const int kv = head2 - (NH + NKV);
#pragma unroll
    for (int i = 0; i < 8; ++i) {
      int m = m0 + wm + (i >> 2) * 64 + (i & 3) * 16 + quad * 4;
      int b = m >> 11, sbase = m & (SEQ - 1);
#pragma unroll
      for (int j = 0; j < 4; ++j) {
        int d = (wave & 1) * 64 + (j >> 1) * 32 + (j & 1) * 16 + l16;
        ushort4 pk;
        pk.x = f2bf(acc[i][j][0]); pk.y = f2bf(acc[i][j][1]);
        pk.z = f2bf(acc[i][j][2]); pk.w = f2bf(acc[i][j][3]);
        *(ushort4*)&Vt[((size_t)(b * NKV + kv) * HD + d) * SEQ + sbase] = pk;
      }
    }
    return;  // tile is all-V: no barrier divergence
  }

  // ---- Q/K path: RMSNorm (head = 128 cols = wave pair) + RoPE + cast ----
  float* pscr = (float*)smem;                      // [8 waves][64 cols][20]
  float* pssq = (float*)(smem + 8 * 64 * 20 * 4);  // [8 waves][16 rows]
  const float* w = (head2 < NH) ? qw : kw;
  float wown[4], wpar[4];
#pragma unroll
  for (int j = 0; j < 4; ++j) {
    int d = (wave & 1) * 64 + (j >> 1) * 32 + (j & 1) * 16 + l16;
    wown[j] = w[d];
    wpar[j] = w[d ^ 64];
  }
#pragma unroll 1
  for (int i = 0; i < 8; ++i) {
    float sq[4];
#pragma unroll
    for (int r = 0; r < 4; ++r) {
      float s2 = acc[i][0][r] * acc[i][0][r] + acc[i][1][r] * acc[i][1][r] +
                 acc[i][2][r] * acc[i][2][r] + acc[i][3][r] * acc[i][3][r];
#pragma unroll
      for (int off = 1; off < 16; off <<= 1) s2 += __shfl_xor(s2, off, 64);
      sq[r] = s2;
    }
    if (l16 == 0)
      *(float4*)&pssq[wave * 16 + quad * 4] = make_float4(sq[0], sq[1], sq[2], sq[3]);
#pragma unroll
    for (int j = 0; j < 4; ++j)
      *(float4*)&pscr[(wave * 64 + j * 16 + l16) * 20 + quad * 4] = *(float4*)&acc[i][j];
    __syncthreads();
    float4 oss = *(const float4*)&pssq[(wave ^ 1) * 16 + quad * 4];
    float rr[4];
    rr[0] = rsqrtf((sq[0] + oss.x) * (1.0f / 128.0f) + 1e-6f);
    rr[1] = rsqrtf((sq[1] + oss.y) * (1.0f / 128.0f) + 1e-6f);
    rr[2] = rsqrtf((sq[2] + oss.z) * (1.0f / 128.0f) + 1e-6f);
    rr[3] = rsqrtf((sq[3] + oss.w) * (1.0f / 128.0f) + 1e-6f);
    int mbase = m0 + wm + (i >> 2) * 64 + (i & 3) * 16 + quad * 4;
    int b = mbase >> 11, sbase = mbase & (SEQ - 1);
#pragma unroll
    for (int j = 0; j < 4; ++j) {
      float4 par = *(const float4*)&pscr[((wave ^ 1) * 64 + j * 16 + l16) * 20 + quad * 4];
      float pr[4] = {par.x, par.y, par.z, par.w};
      int d = (wave & 1) * 64 + (j >> 1) * 32 + (j & 1) * 16 + l16;
      unsigned short* dst = (head2 < NH)
          ? Qb + ((size_t)(b * NH + head2) * SEQ + sbase) * HD + d
          : Kbb + ((size_t)(b * NKV + (head2 - NH)) * SEQ + sbase) * HD + d;
#pragma unroll
      for (int r = 0; r < 4; ++r) {
        int s = sbase + r;
        float c = cosb[s * HD + d], sn = sinb[s * HD + d];
        float xo = acc[i][j][r] * rr[r] * wown[j];
        float xp = pr[r] * rr[r] * wpar[j];
        float out = ((wave & 1) == 0) ? (xo * c - xp * sn) : (xo * c + xp * sn);
        dst[(size_t)r * HD] = f2bf(out);
      }
    }
    __syncthreads();  // pscr/pssq reused next i
  }
}

// ------- O-proj GEMM: BM=256, BN=128 -> grid 16x16 = 256 blocks -------
__global__ __launch_bounds__(512, 1)
void gemm_o_kernel(const unsigned short* __restrict__ A,   // Ob [4096][2048]
                   const unsigned short* __restrict__ Bt,  // wot [2048][2048]
                   float* __restrict__ C) {                // [4096][2048] fp32
  extern __shared__ __align__(16) char smem[];  // 96 KiB: A dbuf 64K | B dbuf 32K
  const int tid = threadIdx.x;
  const int wave = tid >> 6, lane = tid & 63;
  const int quad = lane >> 4, l16 = lane & 15;
  const int nwg = gridDim.x * gridDim.y;
  const int orig = blockIdx.x + gridDim.x * blockIdx.y;
  const int lin = (orig & 7) * (nwg >> 3) + (orig >> 3);
  const int bx = lin % gridDim.x, by = lin / gridDim.x;
  const int m0 = bx * 256, n0 = by * 128;
  const int wm = (wave >> 2) * 128, wn = (wave & 3) * 32;

  const int sgrow = wave * 8 + (lane >> 3);
  const int swzcol = (((lane & 7) ^ ((lane >> 3) & 7)) << 4);
  const int laneA0 = l16 * 128 + ((quad ^ (l16 & 7)) << 4);
  const int laneA1 = laneA0 ^ 64;

  auto stageA = [&](int T, int h) {
    const char* g = (const char*)A + (((size_t)(m0 + h * 128)) * HIDDEN + T * 64) * 2;
    char* l = smem + (size_t)(((T & 1) * 2 + h) * 16384) + wave * 1024;
#pragma unroll
    for (int ii = 0; ii < 2; ++ii) {
      const char* src = g + (size_t)(ii * 64 + sgrow) * (HIDDEN * 2) + swzcol;
      __builtin_amdgcn_global_load_lds(
          (const __attribute__((address_space(1))) unsigned int*)src,
          (__attribute__((address_space(3))) unsigned int*)(l + ii * 8192), 16, 0, 0);
    }
  };
  auto stageB = [&](int T, int h) {  // 64-row half: single issue
    const char* g = (const char*)Bt + (((size_t)(n0 + h * 64)) * HIDDEN + T * 64) * 2;
    char* l = smem + 65536 + (size_t)(((T & 1) * 2 + h) * 8192) + wave * 1024;
    const char* src = g + (size_t)sgrow * (HIDDEN * 2) + swzcol;
    __builtin_amdgcn_global_load_lds(
        (const __attribute__((address_space(1))) unsigned int*)src,
        (__attribute__((address_space(3))) unsigned int*)l, 16, 0, 0);
  };

  floatx4 acc[8][2] = {};
  short8 a[4][2], bAv[2], bBv[2];
  const int NT = HIDDEN / 64;  // 32

  stageA(0, 0); stageA(0, 1); stageB(0, 0); stageB(0, 1);
  stageA(1, 0); stageA(1, 1); stageB(1, 0); stageB(1, 1);
  WAIT_VM(6);
  S_BAR();

#pragma unroll 1
  for (int Y = 0; Y < NT; ++Y) {
    const int cb = Y & 1;
    const char* Ah = smem + (size_t)((cb * 2 + (wave >> 2)) * 16384);
    const char* Bh = smem + 65536 + (size_t)((cb * 2 + ((wave & 3) >> 1)) * 8192) +
                     (wn & 32) * 128;
    // ---- P0: ds a[M0](8) + bAv(2); mfma (M0,N0) ----
#pragma unroll
    for (int fi = 0; fi < 4; ++fi) {
      a[fi][0] = *(const short8*)(Ah + fi * 2048 + laneA0);
      a[fi][1] = *(const short8*)(Ah + fi * 2048 + laneA1);
    }
    bAv[0] = *(const short8*)(Bh + laneA0);
    bAv[1] = *(const short8*)(Bh + laneA1);
    LGKM_HINT8();
    S_BAR();
    WAIT_LGKM0();
    __builtin_amdgcn_s_setprio(1);
#pragma unroll
    for (int fi = 0; fi < 4; ++fi) {
      acc[fi][0] = MFMA16(a[fi][0], bAv[0], acc[fi][0]);
      acc[fi][0] = MFMA16(a[fi][1], bAv[1], acc[fi][0]);
    }
    __builtin_amdgcn_s_setprio(0);
    S_BAR();
    // ---- P1: ds bBv(2); mfma (M0,N1) ----
    bBv[0] = *(const short8*)(Bh + 2048 + laneA0);
    bBv[1] = *(const short8*)(Bh + 2048 + laneA1);
    S_BAR();
    WAIT_LGKM0();
    __builtin_amdgcn_s_setprio(1);
#pragma unroll
    for (int fi = 0; fi < 4; ++fi) {
      acc[fi][1] = MFMA16(a[fi][0], bBv[0], acc[fi][1]);
      acc[fi][1] = MFMA16(a[fi][1], bBv[1], acc[fi][1]);
    }
    __builtin_amdgcn_s_setprio(0);
    S_BAR();
    // ---- P2: ds a[M1](8); stage B0,B1(Y+2); mfma (M1,N1) ----
#pragma unroll
    for (int fi = 0; fi < 4; ++fi) {
      a[fi][0] = *(const short8*)(Ah + 8192 + fi * 2048 + laneA0);
      a[fi][1] = *(const short8*)(Ah + 8192 + fi * 2048 + laneA1);
    }
    if (Y + 2 < NT) { stageB(Y + 2, 0); stageB(Y + 2, 1); }
    S_BAR();
    WAIT_LGKM0();
    __builtin_amdgcn_s_setprio(1);
#pragma unroll
    for (int fi = 0; fi < 4; ++fi) {
      acc[4 + fi][1] = MFMA16(a[fi][0], bBv[0], acc[4 + fi][1]);
      acc[4 + fi][1] = MFMA16(a[fi][1], bBv[1], acc[4 + fi][1]);
    }
    __builtin_amdgcn_s_setprio(0);
    S_BAR();
    // ---- P3: stage A0,A1(Y+2); mfma (M1,N0) ----
    if (Y + 2 < NT) { stageA(Y + 2, 0); stageA(Y + 2, 1); }
    S_BAR();
    __builtin_amdgcn_s_setprio(1);
#pragma unroll
    for (int fi = 0; fi < 4; ++fi) {
      acc[4 + fi][0] = MFMA16(a[fi][0], bAv[0], acc[4 + fi][0]);
      acc[4 + fi][0] = MFMA16(a[fi][1], bAv[1], acc[4 + fi][0]);
    }
    __builtin_amdgcn_s_setprio(0);
    if (Y + 2 < NT) { WAIT_VM(6); } else { WAIT_VM(0); }
    S_BAR();
  }

#pragma unroll
  for (int i = 0; i < 8; ++i) {
    int row = m0 + wm + (i >> 2) * 64 + (i & 3) * 16 + quad * 4;
#pragma unroll
    for (int j = 0; j < 2; ++j) {
      int col = n0 + wn + j * 16 + l16;
#pragma unroll
      for (int r = 0; r < 4; ++r)
        C[(size_t)(row + r) * 2048 + col] = acc[i][j][r];
    }
  }
}

// ------- flash attention (unchanged, verified) -------
__device__ __forceinline__ void stage_rows(const unsigned short* gbase, int rowstride,
                                           unsigned short* lds, int wave, int quad,
                                           int s_cx, int s_hb) {
#pragma unroll
  for (int i = 0; i < 8; ++i) {
    const int row = i * 16 + wave * 4 + quad;                     // row&3 == quad
    const int sck = s_cx ^ (((2 * i + s_hb) & 3) << 2);           // chunk ^ f(row)
    __builtin_amdgcn_global_load_lds(
        (const __attribute__((address_space(1))) unsigned int*)(gbase + (size_t)row * rowstride + sck * 8),
        (__attribute__((address_space(3))) unsigned int*)(lds + (i * 4 + wave) * 512),
        16, 0, 0);
  }
}

__global__ __launch_bounds__(256, 2)
void attn_kernel(const unsigned short* __restrict__ Q,   // [NB][NH][SEQ][HD]
                 const unsigned short* __restrict__ Kb,  // [NB][NKV][SEQ][HD]
                 const unsigned short* __restrict__ Vt,  // [NB][NKV][HD][SEQ]
                 unsigned short* __restrict__ O) {       // [MT][NH*HD]
  __shared__ __align__(16) unsigned short KVs[2][128 * 128];  // 2 x 32 KiB
  const int tid = threadIdx.x;
  const int wave = tid >> 6, lane = tid & 63;
  const int quad = lane >> 4, l16 = lane & 15;
  const int l3 = l16 & 3, s3 = l16 >> 3, s2 = (l16 >> 2) & 1;
  const int bh = blockIdx.x & 31;
  const int pr = blockIdx.x >> 5;                       // 0..15 -> pair (31-pr, pr)
  const int b = bh >> 4, h = bh & 15, kvh = h >> 2;

  const int s_cx = (lane & 15) ^ quad;                  // staging chunk ^ (row&3)
  const int s_hb = wave >> 1;                           // (4*wave+quad)>>3
  const int krbase = 16 * s3 + 8 * s2 + l3;             // permuted K-row base
  const int f_k = l3 | ((2 * s3 + s2) << 2);            // f(krow), j-independent
  const int kvqb = 16 * (quad >> 1) + 8 * (quad & 1);   // kv label base per quad
  const int qsw = (lane & 48) | (quad << 2);            // col->row state shfl base
  const float CS = 0.08838834764831845f;                // 1/sqrt(128)

  const unsigned short* Kg0 = Kb + (size_t)((b * NKV + kvh) * SEQ) * HD;
  const unsigned short* Vg0 = Vt + (size_t)((b * NKV + kvh) * HD) * SEQ;

  int p = 0;
#pragma unroll 1
  for (int seg = 0; seg < 2; ++seg) {
    const int qt = seg ? pr : (31 - pr);
    const int q0 = qt * 64;
    const int nkt = (qt >> 1) + 1;
    const int qglob = q0 + wave * 16 + l16;             // lane's q row

    const unsigned short* Qg = Q + (size_t)((b * NH + h) * SEQ + q0) * HD;
    short8 qf[4];
#pragma unroll
    for (int ks = 0; ks < 4; ++ks)
      qf[ks] = *(const short8*)&Qg[(size_t)(wave * 16 + l16) * HD + ks * 32 + quad * 8];

    floatx4 oacc[8] = {};
    float mrow = -1e30f, lrow = 0.f;

    stage_rows(Kg0, 128, KVs[p], wave, quad, s_cx, s_hb);        // K tile 0
    __syncthreads();

    for (int kt = 0; kt < nkt; ++kt) {
      const unsigned short* KVp = KVs[p];
      // ---- S^T = K @ Q^T : rows=kv (permuted labels), cols=q ----
      floatx4 sc[8] = {};
#pragma unroll
      for (int ks = 0; ks < 4; ++ks) {
        const int cko = ((ks * 4 + quad) ^ f_k) * 8;
#pragma unroll
        for (int j = 0; j < 8; ++j) {
          const short8 kf = *(const short8*)&KVp[(krbase + 32 * (j >> 1) + 4 * (j & 1)) * 128 + cko];
          sc[j] = __builtin_amdgcn_mfma_f32_16x16x32_bf16(kf, qf[ks], sc[j], 0, 0, 0);
        }
      }
      __syncthreads();  // all K reads done; prev PV reads done
      // V_kt overwrites current buffer; prefetch K_{kt+1} into the other one.
      stage_rows(Vg0 + kt * 128, SEQ, KVs[p], wave, quad, s_cx, s_hb);
      if (kt + 1 < nkt)
        stage_rows(Kg0 + (size_t)(kt + 1) * 128 * HD, 128, KVs[p ^ 1], wave, quad, s_cx, s_hb);

      // ---- causal mask (last tile only; kv via relabel formula) ----
      if (kt == nkt - 1) {
#pragma unroll
        for (int j = 0; j < 8; ++j) {
          const int kvj = kt * 128 + 32 * (j >> 1) + 4 * (j & 1) + kvqb;
#pragma unroll
          for (int r = 0; r < 4; ++r)
            if (kvj + r > qglob) sc[j][r] = -1e30f;
        }
      }
      // ---- online softmax: in-lane over 32 kv, cross-quad via 2 shfl_xor ----
      float mx = -1e30f;
#pragma unroll
      for (int j = 0; j < 8; ++j)
        mx = fmaxf(mx, fmaxf(fmaxf(sc[j][0], sc[j][1]), fmaxf(sc[j][2], sc[j][3])));
      mx = fmaxf(mx, __shfl_xor(mx, 16, 64));
      mx = fmaxf(mx, __shfl_xor(mx, 32, 64));
      if (!__all(mx <= mrow + 62.0f)) {   // defer-max: skip rescale when growth small
        const float mnew = fmaxf(mrow, mx);
        const float al = __expf((mrow - mnew) * CS);
        mrow = mnew;
        lrow *= al;
#pragma unroll
        for (int r = 0; r < 4; ++r) {
          const float ar = __shfl(al, qsw + r, 64);     // col-state -> row-space
#pragma unroll
          for (int t = 0; t < 8; ++t) oacc[t][r] *= ar;
        }
      }
      const float mc = mrow * CS;
      float rs = 0.f;
#pragma unroll
      for (int j = 0; j < 8; ++j)
#pragma unroll
        for (int r = 0; r < 4; ++r) {
          const float pe = __expf(sc[j][r] * CS - mc);
          sc[j][r] = pe;
          rs += pe;
        }
      rs += __shfl_xor(rs, 16, 64);
      rs += __shfl_xor(rs, 32, 64);
      lrow += rs;

      // ---- pack P to bf16; lane-local by construction ----
      unsigned int pk[8][2];
#pragma unroll
      for (int j = 0; j < 8; ++j) {
        pk[j][0] = cvt_pk_bf16(sc[j][0], sc[j][1]);
        pk[j][1] = cvt_pk_bf16(sc[j][2], sc[j][3]);
      }
      __syncthreads();  // V ready (drains staging loads)
      // ---- O += P @ V ----
#pragma unroll
      for (int ks = 0; ks < 4; ++ks) {
        union { unsigned int u[4]; short8 s; } au;
        au.u[0] = pk[2 * ks][0];     au.u[1] = pk[2 * ks][1];
        au.u[2] = pk[2 * ks + 1][0]; au.u[3] = pk[2 * ks + 1][1];
#pragma unroll
        for (int t = 0; t < 8; ++t) {
          const int fv = l3 | (((2 * t + s3) & 3) << 2);
          const short8 vf = *(const short8*)&KVp[(t * 16 + l16) * 128 + (((ks * 4 + quad) ^ fv) * 8)];
          oacc[t] = __builtin_amdgcn_mfma_f32_16x16x32_bf16(au.s, vf, oacc[t], 0, 0, 0);
        }
      }
      p ^= 1;
    }
    // ---- epilogue: fetch 1/l per output row, store ----
    float li[4];
#pragma unroll
    for (int r = 0; r < 4; ++r) li[r] = 1.0f / __shfl(lrow, qsw + r, 64);
#pragma unroll
    for (int t = 0; t < 8; ++t) {
      const int col = h * HD + t * 16 + l16;
#pragma unroll
      for (int r = 0; r < 4; ++r) {
        const int row = q0 + wave * 16 + quad * 4 + r;
        O[(size_t)(b * SEQ + row) * (NH * HD) + col] = f2bf(oacc[t][r] * li[r]);
      }
    }
  }
}

extern "C" void kernel_launch(void* const* d_in, const int* in_sizes, int n_in,
                              void* d_out, int out_size, void* d_ws, size_t ws_size,
                              hipStream_t stream) {
  const float* hidden = (const float*)d_in[0];
  const float* cosb   = (const float*)d_in[1];
  const float* sinb   = (const float*)d_in[2];
  const float* Wq     = (const float*)d_in[3];
  const float* Wk     = (const float*)d_in[4];
  const float* Wv     = (const float*)d_in[5];
  const float* Wo     = (const float*)d_in[6];
  const float* qw     = (const float*)d_in[7];
  const float* kw     = (const float*)d_in[8];
  (void)in_sizes; (void)n_in; (void)out_size; (void)ws_size;

  char* ws = (char*)d_ws;
  size_t off = 0;
  auto alloc = [&](size_t n) { char* p = ws + off; off += (n + 255) & ~(size_t)255; return p; };

  unsigned short* hb    = (unsigned short*)alloc((size_t)MT * HIDDEN * 2);   // (16 MB)
  unsigned short* wqkvt = (unsigned short*)alloc((size_t)NQKV * HIDDEN * 2); // (12 MB)
  unsigned short* wot   = (unsigned short*)alloc((size_t)2048 * 2048 * 2);   // (8 MB)
  unsigned short* Qb  = (unsigned short*)alloc((size_t)MT * 2048 * 2);  // (16 MB)
  unsigned short* Kbb = (unsigned short*)alloc((size_t)MT * 512 * 2);   // (4 MB)
  unsigned short* Vtb = (unsigned short*)alloc((size_t)MT * 512 * 2);   // (4 MB)
  unsigned short* Ob  = (unsigned short*)alloc((size_t)MT * 2048 * 2);  // (16 MB)

  static bool attr_done = false;
  if (!attr_done) {
    hipFuncSetAttribute((const void*)gemm_qkv_kernel,
                        hipFuncAttributeMaxDynamicSharedMemorySize, 131072);
    hipFuncSetAttribute((const void*)gemm_o_kernel,
                        hipFuncAttributeMaxDynamicSharedMemorySize, 98304);
    attr_done = true;
  }

  cast_bf16_kernel<<<(MT * HIDDEN / 4) / 256, 256, 0, stream>>>(hidden, hb, MT * HIDDEN / 4);
  dim3 tb(32, 8);
  wtrans_kernel<<<dim3(64, 64, 3), tb, 0, stream>>>(Wq, Wk, Wv, Wo, wqkvt, wot);

  // fused QKV projection + norm/rope/V-transpose epilogue: repaired 8-phase 256x256
  gemm_qkv_kernel<<<dim3(MT / 256, NQKV / 256), 512, 131072, stream>>>(
      hb, wqkvt, qw, kw, cosb, sinb, Qb, Kbb, Vtb);

  // paired q-tiles: 16 pairs x 32 (b,h) = 512 blocks, uniform 17 kv-tiles each
  attn_kernel<<<512, 256, 0, stream>>>(Qb, Kbb, Vtb, Ob);

  // O-projection: repaired 8-phase 256x128 -> 256 blocks (full machine)
  gemm_o_kernel<<<dim3(MT / 256, 2048 / 128), 512, 98304, stream>>>(Ob, wot, (float*)d_out);
}

// Round 4
// 292.682 us; speedup vs baseline: 1.1843x; 1.1843x over previous
//
#include <hip/hip_runtime.h>

typedef float floatx4 __attribute__((ext_vector_type(4)));
typedef short short8 __attribute__((ext_vector_type(8)));

#define HIDDEN 2048
#define NH 16
#define NKV 4
#define HD 128
#define NB 2
#define SEQ 2048
#define MT (NB * SEQ)  // 4096
#define NQKV 3072      // fused projection width: 2048 Q + 512 K + 512 V

__device__ __forceinline__ unsigned short f2bf(float x) {
  union { float f; unsigned u; } v; v.f = x;
  unsigned r = v.u + 0x7FFFu + ((v.u >> 16) & 1u);  // RNE
  return (unsigned short)(r >> 16);
}

__device__ __forceinline__ unsigned int cvt_pk_bf16(float lo, float hi) {
  unsigned int r;
  asm("v_cvt_pk_bf16_f32 %0, %1, %2" : "=v"(r) : "v"(lo), "v"(hi));
  return r;
}

// ---------------- contiguous fp32 -> bf16 cast ----------------
__global__ void cast_bf16_kernel(const float* __restrict__ in,
                                 unsigned short* __restrict__ out, int n4) {
  int i = blockIdx.x * 256 + threadIdx.x;
  if (i >= n4) return;
  float4 v = ((const float4*)in)[i];
  ushort4 o;
  o.x = f2bf(v.x); o.y = f2bf(v.y); o.z = f2bf(v.z); o.w = f2bf(v.w);
  ((ushort4*)out)[i] = o;
}

// ------- fused weight transpose + cast -------
__global__ void wtrans_kernel(const float* __restrict__ Wq,
                              const float* __restrict__ Wk,
                              const float* __restrict__ Wv,
                              const float* __restrict__ Wo,
                              unsigned short* __restrict__ wqkvt,
                              unsigned short* __restrict__ wot) {
  __shared__ float tile[32][33];
  int z = blockIdx.z;
  int nt = blockIdx.x * 32;
  int k0 = blockIdx.y * 32;
  const float* src;
  unsigned short* dst;
  int Nd, scol0, drow0;
  if (z == 0) {
    src = Wq; Nd = 2048; scol0 = nt; drow0 = nt; dst = wqkvt;
  } else if (z == 1) {
    src = Wo; Nd = 2048; scol0 = nt; drow0 = nt; dst = wot;
  } else {
    if (nt >= 1024) return;
    Nd = 512; dst = wqkvt; drow0 = 2048 + nt;
    if (nt < 512) { src = Wk; scol0 = nt; }
    else          { src = Wv; scol0 = nt - 512; }
  }
  int tx = threadIdx.x, ty = threadIdx.y;
  for (int i = 0; i < 32; i += 8)
    tile[ty + i][tx] = src[(size_t)(k0 + ty + i) * Nd + scol0 + tx];
  __syncthreads();
  for (int i = 0; i < 32; i += 8)
    dst[(size_t)(drow0 + ty + i) * HIDDEN + k0 + tx] = f2bf(tile[tx][ty + i]);
}

// =====================================================================
// m97-structure 128x128 GEMM (verified 79us qkv @round-1), upgraded:
//  - BK=64: half the barrier/drain pairs, same 3 blocks/CU occupancy
//  - G4 XOR swizzle: LDS 16B chunk c of row r holds global chunk c^(r&7);
//    inverse applied on the GLOBAL source of global_load_lds (rule #21),
//    read at chunk (kk*4+quad)^(l16&7) -> conflict-free b128 (attn-verified)
//  - bijective XCD remap (grids divisible by 8)
// =====================================================================

// ------- plain C[M][N] fp32 = A @ Bt^T — used for O-proj -------
__global__ __launch_bounds__(256, 3)
void gemm_bf16_kernel(const unsigned short* __restrict__ A,
                      const unsigned short* __restrict__ Bt,
                      float* __restrict__ C, int M, int N, int K) {
  __shared__ unsigned short As[128 * 64];
  __shared__ unsigned short Bs[128 * 64];
  const int tid = threadIdx.x;
  const int wave = tid >> 6, lane = tid & 63;
  const int quad = lane >> 4, l16 = lane & 15;
  // bijective XCD remap (nwg % 8 == 0)
  const int nwg = gridDim.x * gridDim.y;
  const int orig = blockIdx.y * gridDim.x + blockIdx.x;
  const int lin = (orig & 7) * (nwg >> 3) + (orig >> 3);
  const int bx = lin % gridDim.x, by = lin / gridDim.x;
  const int m0 = bx * 128, n0 = by * 128;
  const int wm = (wave >> 1) * 64, wn = (wave & 1) * 64;
  const int srow8 = lane >> 3;                    // 0..7 (row within 8-row slab)
  const int scol = (((lane & 7) ^ srow8) * 8);    // pre-swizzled global col (elems)
  const int rsw = (l16 & 7);                      // row&7 for ds_read swizzle

  floatx4 acc[4][4] = {};

  for (int kt = 0; kt < K; kt += 64) {
    __syncthreads();
#pragma unroll
    for (int t = 0; t < 4; ++t) {
      int row = t * 32 + wave * 8 + srow8;
      __builtin_amdgcn_global_load_lds(
          (const __attribute__((address_space(1))) unsigned int*)&A[(size_t)(m0 + row) * K + kt + scol],
          (__attribute__((address_space(3))) unsigned int*)&As[(t * 32 + wave * 8) * 64],
          16, 0, 0);
    }
#pragma unroll
    for (int t = 0; t < 4; ++t) {
      int row = t * 32 + wave * 8 + srow8;
      __builtin_amdgcn_global_load_lds(
          (const __attribute__((address_space(1))) unsigned int*)&Bt[(size_t)(n0 + row) * K + kt + scol],
          (__attribute__((address_space(3))) unsigned int*)&Bs[(t * 32 + wave * 8) * 64],
          16, 0, 0);
    }
    __syncthreads();
#pragma unroll
    for (int kk = 0; kk < 2; ++kk) {
      const int ck = ((kk * 4 + quad) ^ rsw) * 8;
      short8 af[4], bf[4];
#pragma unroll
      for (int i = 0; i < 4; i++)
        af[i] = *(const short8*)&As[(wm + i * 16 + l16) * 64 + ck];
#pragma unroll
      for (int j = 0; j < 4; j++)
        bf[j] = *(const short8*)&Bs[(wn + j * 16 + l16) * 64 + ck];
#pragma unroll
      for (int i = 0; i < 4; i++)
#pragma unroll
        for (int j = 0; j < 4; j++)
          acc[i][j] = __builtin_amdgcn_mfma_f32_16x16x32_bf16(af[i], bf[j], acc[i][j], 0, 0, 0);
    }
  }
#pragma unroll
  for (int i = 0; i < 4; i++) {
    int row = m0 + wm + i * 16 + quad * 4;
#pragma unroll
    for (int j = 0; j < 4; j++) {
      int col = n0 + wn + j * 16 + l16;
#pragma unroll
      for (int r = 0; r < 4; r++)
        C[(size_t)(row + r) * N + col] = acc[i][j][r];
    }
  }
}

// ------- QKV GEMM with fused RMSNorm+RoPE (Q/K) and V-transpose epilogue -------
// N-tile (128 cols) == exactly one head. heads 0..15 -> Qb, 16..19 -> Kbb, 20..23 -> Vt.
__global__ __launch_bounds__(256, 3)
void gemm_qkv_kernel(const unsigned short* __restrict__ A,    // hb [MT][2048]
                     const unsigned short* __restrict__ Bt,   // wqkvt [3072][2048]
                     const float* __restrict__ qw,
                     const float* __restrict__ kw,
                     const float* __restrict__ cosb,
                     const float* __restrict__ sinb,
                     unsigned short* __restrict__ Qb,   // [NB][NH][SEQ][HD]
                     unsigned short* __restrict__ Kbb,  // [NB][NKV][SEQ][HD]
                     unsigned short* __restrict__ Vt) { // [NB][NKV][HD][SEQ]
  // K-loop tiles and epilogue scratch are never live simultaneously: union them.
  __shared__ __align__(16) char sh[32768];
  unsigned short* As = (unsigned short*)sh;              // [128][64] (16 KB)
  unsigned short* Bs = (unsigned short*)(sh + 16384);    // [128][64] (16 KB)
  float* pscr = (float*)sh;                              // [4][64][20] (20 KB)
  float* pssq = (float*)(sh + 20480);                    // [2][128]   (1 KB)
  const int tid = threadIdx.x;
  const int wave = tid >> 6, lane = tid & 63;
  const int quad = lane >> 4, l16 = lane & 15;
  const int nwg = gridDim.x * gridDim.y;
  const int orig = blockIdx.y * gridDim.x + blockIdx.x;
  const int lin = (orig & 7) * (nwg >> 3) + (orig >> 3);
  const int bx = lin % gridDim.x, by = lin / gridDim.x;
  const int m0 = bx * 128, n0 = by * 128;
  const int wm = (wave >> 1) * 64, wn = (wave & 1) * 64;
  const int srow8 = lane >> 3;
  const int scol = (((lane & 7) ^ srow8) * 8);
  const int rsw = (l16 & 7);

  floatx4 acc[4][4] = {};

  for (int kt = 0; kt < HIDDEN; kt += 64) {
    __syncthreads();
#pragma unroll
    for (int t = 0; t < 4; ++t) {
      int row = t * 32 + wave * 8 + srow8;
      __builtin_amdgcn_global_load_lds(
          (const __attribute__((address_space(1))) unsigned int*)&A[(size_t)(m0 + row) * HIDDEN + kt + scol],
          (__attribute__((address_space(3))) unsigned int*)&As[(t * 32 + wave * 8) * 64],
          16, 0, 0);
    }
#pragma unroll
    for (int t = 0; t < 4; ++t) {
      int row = t * 32 + wave * 8 + srow8;
      __builtin_amdgcn_global_load_lds(
          (const __attribute__((address_space(1))) unsigned int*)&Bt[(size_t)(n0 + row) * HIDDEN + kt + scol],
          (__attribute__((address_space(3))) unsigned int*)&Bs[(t * 32 + wave * 8) * 64],
          16, 0, 0);
    }
    __syncthreads();
#pragma unroll
    for (int kk = 0; kk < 2; ++kk) {
      const int ck = ((kk * 4 + quad) ^ rsw) * 8;
      short8 af[4], bf[4];
#pragma unroll
      for (int i = 0; i < 4; i++)
        af[i] = *(const short8*)&As[(wm + i * 16 + l16) * 64 + ck];
#pragma unroll
      for (int j = 0; j < 4; j++)
        bf[j] = *(const short8*)&Bs[(wn + j * 16 + l16) * 64 + ck];
#pragma unroll
      for (int i = 0; i < 4; i++)
#pragma unroll
        for (int j = 0; j < 4; j++)
          acc[i][j] = __builtin_amdgcn_mfma_f32_16x16x32_bf16(af[i], bf[j], acc[i][j], 0, 0, 0);
    }
  }

  const int head = n0 >> 7;
  if (head >= NH + NKV) {
    // ---- V path: cast + write transposed Vt[b][kv][d][s] (s packed x4) ----
    const int kv = head - (NH + NKV);
#pragma unroll
    for (int i = 0; i < 4; ++i) {
      int m = m0 + wm + i * 16 + quad * 4;
      int b = m >> 11, sbase = m & (SEQ - 1);
#pragma unroll
      for (int j = 0; j < 4; ++j) {
        int d = wn + j * 16 + l16;
        ushort4 pk;
        pk.x = f2bf(acc[i][j][0]); pk.y = f2bf(acc[i][j][1]);
        pk.z = f2bf(acc[i][j][2]); pk.w = f2bf(acc[i][j][3]);
        *(ushort4*)&Vt[((size_t)(b * NKV + kv) * HD + d) * SEQ + sbase] = pk;
      }
    }
    return;  // head is block-uniform: no barrier divergence
  }

  // ---- Q/K path: RMSNorm (over 128 cols = full head) + RoPE + cast ----
  __syncthreads();  // all waves done reading As/Bs before pscr/pssq reuse the LDS
  const float* w = (head < NH) ? qw : kw;
  float wown[4], wpar[4];
#pragma unroll
  for (int j = 0; j < 4; ++j) {
    wown[j] = w[wn + j * 16 + l16];
    wpar[j] = w[(wn ^ 64) + j * 16 + l16];
  }
#pragma unroll
  for (int i = 0; i < 4; ++i) {
    // partial sum-of-squares per row over this wave's 64 cols
    float sq[4];
#pragma unroll
    for (int r = 0; r < 4; ++r) {
      float s2 = acc[i][0][r] * acc[i][0][r] + acc[i][1][r] * acc[i][1][r] +
                 acc[i][2][r] * acc[i][2][r] + acc[i][3][r] * acc[i][3][r];
#pragma unroll
      for (int off = 1; off < 16; off <<= 1) s2 += __shfl_xor(s2, off, 64);
      sq[r] = s2;
    }
    if (l16 == 0)
      *(float4*)&pssq[(wn >> 6) * 128 + wm + i * 16 + quad * 4] = make_float4(sq[0], sq[1], sq[2], sq[3]);
    // publish raw acc for the partner col-half (RoPE needs x[d^64])
#pragma unroll
    for (int j = 0; j < 4; ++j)
      *(float4*)&pscr[(wave * 64 + j * 16 + l16) * 20 + quad * 4] = *(float4*)&acc[i][j];
    __syncthreads();
    float4 oss = *(const float4*)&pssq[((wn >> 6) ^ 1) * 128 + wm + i * 16 + quad * 4];
    float rr[4];
    rr[0] = rsqrtf((sq[0] + oss.x) * (1.0f / 128.0f) + 1e-6f);
    rr[1] = rsqrtf((sq[1] + oss.y) * (1.0f / 128.0f) + 1e-6f);
    rr[2] = rsqrtf((sq[2] + oss.z) * (1.0f / 128.0f) + 1e-6f);
    rr[3] = rsqrtf((sq[3] + oss.w) * (1.0f / 128.0f) + 1e-6f);
    int mbase = m0 + wm + i * 16 + quad * 4;
    int b = mbase >> 11, sbase = mbase & (SEQ - 1);
#pragma unroll
    for (int j = 0; j < 4; ++j) {
      float4 par = *(const float4*)&pscr[((wave ^ 1) * 64 + j * 16 + l16) * 20 + quad * 4];
      float pr[4] = {par.x, par.y, par.z, par.w};
      int d = wn + j * 16 + l16;
      unsigned short* dst = (head < NH)
          ? Qb + ((size_t)(b * NH + head) * SEQ + sbase) * HD + d
          : Kbb + ((size_t)(b * NKV + (head - NH)) * SEQ + sbase) * HD + d;
#pragma unroll
      for (int r = 0; r < 4; ++r) {
        int s = sbase + r;
        float c = cosb[s * HD + d], sn = sinb[s * HD + d];
        float xo = acc[i][j][r] * rr[r] * wown[j];
        float xp = pr[r] * rr[r] * wpar[j];
        float out = (wn == 0) ? (xo * c - xp * sn) : (xo * c + xp * sn);
        dst[(size_t)r * HD] = f2bf(out);
      }
    }
    __syncthreads();  // pscr/pssq reused next i
  }
}

// ------- flash attention (unchanged, verified round-1) -------
__device__ __forceinline__ void stage_rows(const unsigned short* gbase, int rowstride,
                                           unsigned short* lds, int wave, int quad,
                                           int s_cx, int s_hb) {
#pragma unroll
  for (int i = 0; i < 8; ++i) {
    const int row = i * 16 + wave * 4 + quad;                     // row&3 == quad
    const int sck = s_cx ^ (((2 * i + s_hb) & 3) << 2);           // chunk ^ f(row)
    __builtin_amdgcn_global_load_lds(
        (const __attribute__((address_space(1))) unsigned int*)(gbase + (size_t)row * rowstride + sck * 8),
        (__attribute__((address_space(3))) unsigned int*)(lds + (i * 4 + wave) * 512),
        16, 0, 0);
  }
}

__global__ __launch_bounds__(256, 2)
void attn_kernel(const unsigned short* __restrict__ Q,   // [NB][NH][SEQ][HD]
                 const unsigned short* __restrict__ Kb,  // [NB][NKV][SEQ][HD]
                 const unsigned short* __restrict__ Vt,  // [NB][NKV][HD][SEQ]
                 unsigned short* __restrict__ O) {       // [MT][NH*HD]
  __shared__ __align__(16) unsigned short KVs[2][128 * 128];  // 2 x 32 KiB
  const int tid = threadIdx.x;
  const int wave = tid >> 6, lane = tid & 63;
  const int quad = lane >> 4, l16 = lane & 15;
  const int l3 = l16 & 3, s3 = l16 >> 3, s2 = (l16 >> 2) & 1;
  const int bh = blockIdx.x & 31;
  const int pr = blockIdx.x >> 5;                       // 0..15 -> pair (31-pr, pr)
  const int b = bh >> 4, h = bh & 15, kvh = h >> 2;

  const int s_cx = (lane & 15) ^ quad;                  // staging chunk ^ (row&3)
  const int s_hb = wave >> 1;                           // (4*wave+quad)>>3
  const int krbase = 16 * s3 + 8 * s2 + l3;             // permuted K-row base
  const int f_k = l3 | ((2 * s3 + s2) << 2);            // f(krow), j-independent
  const int kvqb = 16 * (quad >> 1) + 8 * (quad & 1);   // kv label base per quad
  const int qsw = (lane & 48) | (quad << 2);            // col->row state shfl base
  const float CS = 0.08838834764831845f;                // 1/sqrt(128)

  const unsigned short* Kg0 = Kb + (size_t)((b * NKV + kvh) * SEQ) * HD;
  const unsigned short* Vg0 = Vt + (size_t)((b * NKV + kvh) * HD) * SEQ;

  int p = 0;
#pragma unroll 1
  for (int seg = 0; seg < 2; ++seg) {
    const int qt = seg ? pr : (31 - pr);
    const int q0 = qt * 64;
    const int nkt = (qt >> 1) + 1;
    const int qglob = q0 + wave * 16 + l16;             // lane's q row

    const unsigned short* Qg = Q + (size_t)((b * NH + h) * SEQ + q0) * HD;
    short8 qf[4];
#pragma unroll
    for (int ks = 0; ks < 4; ++ks)
      qf[ks] = *(const short8*)&Qg[(size_t)(wave * 16 + l16) * HD + ks * 32 + quad * 8];

    floatx4 oacc[8] = {};
    float mrow = -1e30f, lrow = 0.f;

    stage_rows(Kg0, 128, KVs[p], wave, quad, s_cx, s_hb);        // K tile 0
    __syncthreads();

    for (int kt = 0; kt < nkt; ++kt) {
      const unsigned short* KVp = KVs[p];
      // ---- S^T = K @ Q^T : rows=kv (permuted labels), cols=q ----
      floatx4 sc[8] = {};
#pragma unroll
      for (int ks = 0; ks < 4; ++ks) {
        const int cko = ((ks * 4 + quad) ^ f_k) * 8;
#pragma unroll
        for (int j = 0; j < 8; ++j) {
          const short8 kf = *(const short8*)&KVp[(krbase + 32 * (j >> 1) + 4 * (j & 1)) * 128 + cko];
          sc[j] = __builtin_amdgcn_mfma_f32_16x16x32_bf16(kf, qf[ks], sc[j], 0, 0, 0);
        }
      }
      __syncthreads();  // all K reads done; prev PV reads done
      // V_kt overwrites current buffer; prefetch K_{kt+1} into the other one.
      stage_rows(Vg0 + kt * 128, SEQ, KVs[p], wave, quad, s_cx, s_hb);
      if (kt + 1 < nkt)
        stage_rows(Kg0 + (size_t)(kt + 1) * 128 * HD, 128, KVs[p ^ 1], wave, quad, s_cx, s_hb);

      // ---- causal mask (last tile only; kv via relabel formula) ----
      if (kt == nkt - 1) {
#pragma unroll
        for (int j = 0; j < 8; ++j) {
          const int kvj = kt * 128 + 32 * (j >> 1) + 4 * (j & 1) + kvqb;
#pragma unroll
          for (int r = 0; r < 4; ++r)
            if (kvj + r > qglob) sc[j][r] = -1e30f;
        }
      }
      // ---- online softmax: in-lane over 32 kv, cross-quad via 2 shfl_xor ----
      float mx = -1e30f;
#pragma unroll
      for (int j = 0; j < 8; ++j)
        mx = fmaxf(mx, fmaxf(fmaxf(sc[j][0], sc[j][1]), fmaxf(sc[j][2], sc[j][3])));
      mx = fmaxf(mx, __shfl_xor(mx, 16, 64));
      mx = fmaxf(mx, __shfl_xor(mx, 32, 64));
      if (!__all(mx <= mrow + 62.0f)) {   // defer-max: skip rescale when growth small
        const float mnew = fmaxf(mrow, mx);
        const float al = __expf((mrow - mnew) * CS);
        mrow = mnew;
        lrow *= al;
#pragma unroll
        for (int r = 0; r < 4; ++r) {
          const float ar = __shfl(al, qsw + r, 64);     // col-state -> row-space
#pragma unroll
          for (int t = 0; t < 8; ++t) oacc[t][r] *= ar;
        }
      }
      const float mc = mrow * CS;
      float rs = 0.f;
#pragma unroll
      for (int j = 0; j < 8; ++j)
#pragma unroll
        for (int r = 0; r < 4; ++r) {
          const float pe = __expf(sc[j][r] * CS - mc);
          sc[j][r] = pe;
          rs += pe;
        }
      rs += __shfl_xor(rs, 16, 64);
      rs += __shfl_xor(rs, 32, 64);
      lrow += rs;

      // ---- pack P to bf16; lane-local by construction ----
      unsigned int pk[8][2];
#pragma unroll
      for (int j = 0; j < 8; ++j) {
        pk[j][0] = cvt_pk_bf16(sc[j][0], sc[j][1]);
        pk[j][1] = cvt_pk_bf16(sc[j][2], sc[j][3]);
      }
      __syncthreads();  // V ready (drains staging loads)
      // ---- O += P @ V ----
#pragma unroll
      for (int ks = 0; ks < 4; ++ks) {
        union { unsigned int u[4]; short8 s; } au;
        au.u[0] = pk[2 * ks][0];     au.u[1] = pk[2 * ks][1];
        au.u[2] = pk[2 * ks + 1][0]; au.u[3] = pk[2 * ks + 1][1];
#pragma unroll
        for (int t = 0; t < 8; ++t) {
          const int fv = l3 | (((2 * t + s3) & 3) << 2);
          const short8 vf = *(const short8*)&KVp[(t * 16 + l16) * 128 + (((ks * 4 + quad) ^ fv) * 8)];
          oacc[t] = __builtin_amdgcn_mfma_f32_16x16x32_bf16(au.s, vf, oacc[t], 0, 0, 0);
        }
      }
      p ^= 1;
    }
    // ---- epilogue: fetch 1/l per output row, store ----
    float li[4];
#pragma unroll
    for (int r = 0; r < 4; ++r) li[r] = 1.0f / __shfl(lrow, qsw + r, 64);
#pragma unroll
    for (int t = 0; t < 8; ++t) {
      const int col = h * HD + t * 16 + l16;
#pragma unroll
      for (int r = 0; r < 4; ++r) {
        const int row = q0 + wave * 16 + quad * 4 + r;
        O[(size_t)(b * SEQ + row) * (NH * HD) + col] = f2bf(oacc[t][r] * li[r]);
      }
    }
  }
}

extern "C" void kernel_launch(void* const* d_in, const int* in_sizes, int n_in,
                              void* d_out, int out_size, void* d_ws, size_t ws_size,
                              hipStream_t stream) {
  const float* hidden = (const float*)d_in[0];
  const float* cosb   = (const float*)d_in[1];
  const float* sinb   = (const float*)d_in[2];
  const float* Wq     = (const float*)d_in[3];
  const float* Wk     = (const float*)d_in[4];
  const float* Wv     = (const float*)d_in[5];
  const float* Wo     = (const float*)d_in[6];
  const float* qw     = (const float*)d_in[7];
  const float* kw     = (const float*)d_in[8];
  (void)in_sizes; (void)n_in; (void)out_size; (void)ws_size;

  char* ws = (char*)d_ws;
  size_t off = 0;
  auto alloc = [&](size_t n) { char* p = ws + off; off += (n + 255) & ~(size_t)255; return p; };

  unsigned short* hb    = (unsigned short*)alloc((size_t)MT * HIDDEN * 2);   // (16 MB)
  unsigned short* wqkvt = (unsigned short*)alloc((size_t)NQKV * HIDDEN * 2); // (12 MB)
  unsigned short* wot   = (unsigned short*)alloc((size_t)2048 * 2048 * 2);   // (8 MB)
  unsigned short* Qb  = (unsigned short*)alloc((size_t)MT * 2048 * 2);  // (16 MB)
  unsigned short* Kbb = (unsigned short*)alloc((size_t)MT * 512 * 2);   // (4 MB)
  unsigned short* Vtb = (unsigned short*)alloc((size_t)MT * 512 * 2);   // (4 MB)
  unsigned short* Ob  = (unsigned short*)alloc((size_t)MT * 2048 * 2);  // (16 MB)

  cast_bf16_kernel<<<(MT * HIDDEN / 4) / 256, 256, 0, stream>>>(hidden, hb, MT * HIDDEN / 4);
  dim3 tb(32, 8);
  wtrans_kernel<<<dim3(64, 64, 3), tb, 0, stream>>>(Wq, Wk, Wv, Wo, wqkvt, wot);

  // fused QKV projection + norm/rope/V-transpose epilogue: grid 32x24 = 768 blocks
  gemm_qkv_kernel<<<dim3(MT / 128, NQKV / 128), 256, 0, stream>>>(
      hb, wqkvt, qw, kw, cosb, sinb, Qb, Kbb, Vtb);

  // paired q-tiles: 16 pairs x 32 (b,h) = 512 blocks, uniform 17 kv-tiles each
  attn_kernel<<<512, 256, 0, stream>>>(Qb, Kbb, Vtb, Ob);

  gemm_bf16_kernel<<<dim3(MT / 128, 16), 256, 0, stream>>>(Ob, wot, (float*)d_out, MT, 2048, 2048);
}